// Round 1
// baseline (412.566 us; speedup 1.0000x reference)
//
#include <hip/hip_runtime.h>
#include <math.h>

#define NRAYS 65536
#define T0N 128
#define T1N 64
#define CN 16
#define RPB 4                   // rays (waves) per block
#define NBLK (NRAYS / RPB)      // 16384

#define IMG_OFF   0
#define DEPTH_OFF (NRAYS * 3)
#define FXYZ_OFF  (NRAYS * 4)
#define PROP_OFF  (NRAYS * 7)
#define DIST_OFF  (NRAYS * 7 + 1)

// v_rcp_f32: 1-ulp reciprocal. Output threshold is 1.57e-2 absolute with 4x
// margin at fp32-divide precision — 2^-22 relative error is invisible here.
__device__ __forceinline__ float frcp(float x) { return __builtin_amdgcn_rcpf(x); }

// ---- DPP cross-lane (VALU pipe, zero LDS traffic) ----
template <int CTRL, int RM, int BM, bool BC>
__device__ __forceinline__ float dpp_add(float x) {
  int t = __builtin_amdgcn_update_dpp(0, __float_as_int(x), CTRL, RM, BM, BC);
  return x + __int_as_float(t);
}

// inclusive prefix sum over 64 lanes (gfx9 DPP scan idiom)
__device__ __forceinline__ float scan_incl(float x) {
  x = dpp_add<0x111, 0xF, 0xF, true>(x);   // row_shr:1
  x = dpp_add<0x112, 0xF, 0xF, true>(x);   // row_shr:2
  x = dpp_add<0x114, 0xF, 0xF, true>(x);   // row_shr:4
  x = dpp_add<0x118, 0xF, 0xF, true>(x);   // row_shr:8
  x = dpp_add<0x142, 0xA, 0xF, false>(x);  // row_bcast:15 -> rows 1,3
  x = dpp_add<0x143, 0xC, 0xF, false>(x);  // row_bcast:31 -> rows 2,3
  return x;
}

// wave sum; total valid ONLY in lanes 48..63 (row 3)
__device__ __forceinline__ float reduce_hi(float x) {
  x = dpp_add<0xB1, 0xF, 0xF, true>(x);    // quad_perm xor1
  x = dpp_add<0x4E, 0xF, 0xF, true>(x);    // quad_perm xor2
  x = dpp_add<0x141, 0xF, 0xF, true>(x);   // row_half_mirror
  x = dpp_add<0x140, 0xF, 0xF, true>(x);   // row_mirror
  x = dpp_add<0x142, 0xA, 0xF, false>(x);  // bcast15
  x = dpp_add<0x143, 0xC, 0xF, false>(x);  // bcast31 -> row3 = total
  return x;
}

__device__ __forceinline__ float rl63(float x) {  // broadcast lane63 via SALU
  return __int_as_float(__builtin_amdgcn_readlane(__float_as_int(x), 63));
}

// Wave-internal LDS producer->consumer sync (arrays are wave-private):
// waits lgkmcnt only, does NOT drain vmcnt like __syncthreads.
__device__ __forceinline__ void wave_lds_sync() {
  __builtin_amdgcn_wave_barrier();
  __builtin_amdgcn_fence(__ATOMIC_ACQ_REL, "workgroup");
  __builtin_amdgcn_wave_barrier();
}

__device__ __forceinline__ float spacing_fn(float x) {
  return (x < 1.0f) ? (x * 0.5f) : (1.0f - 0.5f * frcp(x));
}
__device__ __forceinline__ float spacing_inv_fn(float x) {
  return (x < 0.5f) ? (2.0f * x) : frcp(2.0f - 2.0f * x);
}

__device__ __forceinline__ int clampi(int v, int lo, int hi) {
  return min(max(v, lo), hi);
}

__global__ void __launch_bounds__(256) nerf_main(
    const float* __restrict__ rays_o, const float* __restrict__ rays_d,
    const float* __restrict__ aabb, const float* __restrict__ sig_c,
    const float* __restrict__ sig_f, const float* __restrict__ colors,
    const float* __restrict__ w_view, const float* __restrict__ b_view,
    float* __restrict__ out, float* __restrict__ ws_partials, int use_atomic) {
  // s_cdf: 129 real + 3 sentinels (c==129 impossible-in-practice guard)
  __shared__ float s_cdf[RPB][132];
  // scatter-histogram difference arrays (all searchsorted inversions):
  //   [0..65]    dSmp  (66)  — sample_pdf inds
  //   [68..196]  dLo   (129) — interlevel inds_lo counts
  //   [200..328] dHi   (129) — interlevel inds_hi counts
  __shared__ __align__(16) float s_dif[RPB][400];
  __shared__ float s_cw1[RPB][65];
  __shared__ float s_scal[RPB][2];

  const int wv = threadIdx.x >> 6;
  const int lane = threadIdx.x & 63;
  const int ray = blockIdx.x * RPB + wv;

  // ---- zero the diff arrays (wave-private; in-order LDS per wave means the
  // later ds_add_f32 scatters need no extra sync after these stores)
  {
    float4 z4 = make_float4(0.0f, 0.0f, 0.0f, 0.0f);
    float4* zp = (float4*)&s_dif[wv][0];
    zp[lane] = z4;                        // floats 0..255
    if (lane < 36) zp[64 + lane] = z4;    // floats 256..399
  }

  // ---- prefetch colors (4x 1KiB coalesced float4/wave) + sigmas; consumed late
  const int tg = lane >> 2, cg = lane & 3;
  const float4* col4 = (const float4*)(colors + (size_t)ray * (T1N * CN));
  const float4 cva = col4[(tg + 0) * 4 + cg];
  const float4 cvb = col4[(tg + 16) * 4 + cg];
  const float4 cvc = col4[(tg + 32) * 4 + cg];
  const float4 cvd = col4[(tg + 48) * 4 + cg];
  const float2 sg = ((const float2*)sig_c)[ray * 64 + lane];
  const float sgf = sig_f[ray * 64 + lane];
  // w_view rows for channels 4cg..4cg+3 as 3x float4 (was 12 scalar loads, late)
  const float4 wv4a = *(const float4*)(w_view + cg * 12);
  const float4 wv4b = *(const float4*)(w_view + cg * 12 + 4);
  const float4 wv4c = *(const float4*)(w_view + cg * 12 + 8);
  const float bpre = b_view[clampi(lane - 48, 0, 2)];  // lanes 48..50 get b_view[0..2]

  // ---- ray setup (rcp instead of full-precision divide)
  float ro[3], rd[3];
#pragma unroll
  for (int c = 0; c < 3; ++c) { ro[c] = rays_o[ray * 3 + c]; rd[c] = rays_d[ray * 3 + c]; }
  float near = -3.0e38f, far = 3.0e38f;
#pragma unroll
  for (int c = 0; c < 3; ++c) {
    const float rdd = frcp(rd[c] + 1e-15f);
    float ta = (aabb[c] - ro[c]) * rdd;
    float tb = (aabb[c + 3] - ro[c]) * rdd;
    near = fmaxf(near, fminf(ta, tb));
    far = fminf(far, fmaxf(ta, tb));
  }
  if (far < near) { near = 1e9f; far = 1e9f; }
  near = fmaxf(near, 0.05f);
  const float s_near = spacing_fn(near), s_far = spacing_fn(far);

  // ---- coarse level: lane owns bins0 samples 2l, 2l+1
  const int i0 = 2 * lane, i1 = 2 * lane + 1;
  const float b_a = (float)i0 * (1.0f / 128.0f);
  const float b_b = (float)i1 * (1.0f / 128.0f);
  const float b_c = (float)(i1 + 1) * (1.0f / 128.0f);
  const float rb_a = spacing_inv_fn(s_near * (1.0f - b_a) + s_far * b_a);
  const float rb_b = spacing_inv_fn(s_near * (1.0f - b_b) + s_far * b_b);
  const float rb_c = spacing_inv_fn(s_near * (1.0f - b_c) + s_far * b_c);
  const float ds0 = (rb_b - rb_a) * sg.x;
  const float ds1 = (rb_c - rb_b) * sg.y;
  const float Spr = scan_incl(ds0 + ds1);
  const float E0 = Spr - (ds0 + ds1);
  const float e0 = __expf(-E0);
  const float ed0 = __expf(-ds0);
  float w00 = (1.0f - ed0) * e0;
  float w01 = (1.0f - __expf(-ds1)) * (e0 * ed0);
  if (w00 != w00) w00 = 0.0f;  // nan_to_num
  if (w01 != w01) w01 = 0.0f;

  // ---- pdf/cdf: one scan, total from lane 63 via readlane (SALU)
  const float wp0 = w00 + 0.01f, wp1 = w01 + 0.01f;
  const float S2 = scan_incl(wp0 + wp1);
  const float rt = frcp(rl63(S2));
  const float cdfA = fminf((S2 - wp1) * rt, 1.0f);  // cdf[2l+1]
  const float cdfB = fminf(S2 * rt, 1.0f);          // cdf[2l+2]
  s_cdf[wv][i0 + 1] = cdfA;
  s_cdf[wv][i1 + 1] = cdfB;
  if (lane == 0) s_cdf[wv][0] = 0.0f;
  if (lane < 3) s_cdf[wv][129 + lane] = 2.0f;  // guard for (impossible) c==129

  // ---- sample-search inversion: K_i = first j with u_j >= cdf_i,
  // u_j = (j+0.5)/65  =>  K = ceil(65*cdf - 0.5), bucket 65 = "never".
  {
    float* dS = &s_dif[wv][0];
    const int KA = clampi((int)ceilf(fmaf(65.0f, cdfA, -0.5f)), 0, 65);
    const int KB = clampi((int)ceilf(fmaf(65.0f, cdfB, -0.5f)), 0, 65);
    atomicAdd(&dS[KA], 1.0f);
    atomicAdd(&dS[KB], 1.0f);
  }
  wave_lds_sync();  // s_cdf + dSmp ready

  // ---- inverse-CDF sampling of 65 new bins via histogram prefix-scan
  // inds_j = 1 + sum_{k<=j} dSmp[k]   (cdf[0]=0 always counted)
  const float* dS = &s_dif[wv][0];
  const float dme = dS[lane];
  const float Ps = scan_incl(dme);
  const float d64 = dS[64];            // uniform broadcast read
  const int c = 1 + (int)Ps;
  const float c0 = s_cdf[wv][c - 1], c1 = s_cdf[wv][c];
  const float u = ((float)lane + 0.5f) * (1.0f / 65.0f);
  float t = (u - c0) * frcp(c1 - c0);
  t = fminf(fmaxf(t, 0.0f), 1.0f);     // NaN->0, inf->1 == nan_to_num+clip
  const float b0f = (float)(c - 1) * (1.0f / 128.0f);
  const float bv = fmaf(t, 1.0f / 128.0f, b0f);
  // sample j=64: uniform across lanes (replaces the masked lane-63 8-deep chain)
  const int c64 = 1 + (int)(rl63(Ps) + d64);
  const float C0 = s_cdf[wv][c64 - 1], C1 = s_cdf[wv][c64];
  const float u64v = 64.5f * (1.0f / 65.0f);
  float t64 = (u64v - C0) * frcp(C1 - C0);
  t64 = fminf(fmaxf(t64, 0.0f), 1.0f);
  const float bv64 = fmaf(t64, 1.0f / 128.0f, (float)(c64 - 1) * (1.0f / 128.0f));
  float bvn = __shfl_down(bv, 1, 64);                 // bins1[lane+1]
  if (lane == 63) bvn = bv64;

  // ---- interlevel-search inversion, keys straight from registers:
  // countLo_i = #{j in [0,63]: b1_j <= i/128}      => scatter at ceil(128*b1_j)
  // countHi_i = #{j in [1,64]: b1_j <= (i+1)/128}  => scatter at ceil(128*b1_j)-1
  {
    float* dLo = &s_dif[wv][68];
    float* dHi = &s_dif[wv][200];
    const int KL = clampi((int)ceilf(128.0f * bv), 0, 128);
    atomicAdd(&dLo[KL], 1.0f);
    const float bH = (lane == 0) ? bv64 : bv;  // lane0 carries j=64, others j=lane
    const int KH = clampi((int)ceilf(128.0f * bH) - 1, 0, 128);
    atomicAdd(&dHi[KH], 1.0f);
  }

  // ---- fine level: lane owns sample t=lane
  const float rbl  = spacing_inv_fn(s_near * (1.0f - bv)  + s_far * bv);
  const float rbl1 = spacing_inv_fn(s_near * (1.0f - bvn) + s_far * bvn);
  const float dsf = (rbl1 - rbl) * sgf;
  const float Sf = scan_incl(dsf);
  float w1 = (1.0f - __expf(-dsf)) * __expf(-(Sf - dsf));
  if (w1 != w1) w1 = 0.0f;
  const float tmid = 0.5f * (rbl + rbl1);

  // xyz + MERF contraction
  float px = ro[0] + rd[0] * tmid;
  float py = ro[1] + rd[1] * tmid;
  float pz = ro[2] + rd[2] * tmid;
  float cx = px, cy = py, cz = pz;
  {
    float ax = fabsf(px), ay = fabsf(py), az = fabsf(pz);
    float mag = fmaxf(ax, fmaxf(ay, az));
    if (mag >= 1.0f) {
      float inv = frcp(mag);
      float so = (2.0f - inv) * inv;
      int idx = (ax >= ay && ax >= az) ? 0 : ((ay >= az) ? 1 : 2);
      cx = px * (idx == 0 ? so : inv);
      cy = py * (idx == 1 ? so : inv);
      cz = pz * (idx == 2 ? so : inv);
    }
  }

  const float Scw = scan_incl(w1);
  const float wsum = rl63(Scw);
  const float depth_h = reduce_hi(w1 * tmid);   // totals valid lanes 48-63
  const float fx_h = reduce_hi(w1 * cx);
  const float fy_h = reduce_hi(w1 * cy);
  const float fz_h = reduce_hi(w1 * cz);
  s_cw1[wv][lane + 1] = Scw;
  if (lane == 0) s_cw1[wv][0] = 0.0f;

  // ---- distortion loss
  const float interval = bvn - bv;
  const float mid = bv + interval * 0.5f;
  const float wm = w1 * mid;
  const float Swm = scan_incl(wm);
  const float dl = (1.0f / 3.0f) * (interval * w1 * w1) +
                   2.0f * (wm * (Scw - w1) - w1 * (Swm - wm));
  const float dist_h = reduce_hi(dl);
  wave_lds_sync();  // covers s_cw1 + dLo/dHi scatters before interlevel reads

  // ---- interlevel loss: counts recovered by two prefix scans (2 entries/lane)
  float prop_lane;
  {
    const float* cwp = &s_cw1[wv][0];
    const float2 dL = ((const float2*)&s_dif[wv][68])[lane];   // dLo[2l], dLo[2l+1]
    const float2 dH = ((const float2*)&s_dif[wv][200])[lane];  // dHi[2l], dHi[2l+1]
    const float sL = scan_incl(dL.x + dL.y);
    const float sH = scan_incl(dH.x + dH.y);
    const int iloA = clampi((int)(sL - dL.y) - 1, 0, 63);      // i = 2l
    const int iloB = clampi((int)sL - 1, 0, 63);               // i = 2l+1
    const int ihiA = min((int)(sH - dH.y), 63);
    const int ihiB = min((int)sH, 63);
    const float wA = cwp[ihiA + 1] - cwp[iloA];
    const float wB = cwp[ihiB + 1] - cwp[iloB];
    const float dA = fmaxf(w00 - wA, 0.0f);
    const float dB = fmaxf(w01 - wB, 0.0f);
    prop_lane = dA * dA * frcp(w00 + 1e-8f) + dB * dB * frcp(w01 + 1e-8f);
  }
  const float prop_h = reduce_hi(prop_lane);

  // ---- color pipeline: fuse w_view matvec BEFORE the wave reduction
  float acc0, acc1, acc2;
  {
    const float wvv0 = __shfl(w1, tg, 64);
    const float wvv1 = __shfl(w1, tg + 16, 64);
    const float wvv2 = __shfl(w1, tg + 32, 64);
    const float wvv3 = __shfl(w1, tg + 48, 64);
    const float a0 = fmaf(wvv0, cva.x, fmaf(wvv1, cvb.x, fmaf(wvv2, cvc.x, wvv3 * cvd.x)));
    const float a1 = fmaf(wvv0, cva.y, fmaf(wvv1, cvb.y, fmaf(wvv2, cvc.y, wvv3 * cvd.y)));
    const float a2 = fmaf(wvv0, cva.z, fmaf(wvv1, cvb.z, fmaf(wvv2, cvc.z, wvv3 * cvd.z)));
    const float a3 = fmaf(wvv0, cva.w, fmaf(wvv1, cvb.w, fmaf(wvv2, cvc.w, wvv3 * cvd.w)));
    // wvp[k] = wv4{a,b,c} lanes: [0,3,6,9]=col0, [1,4,7,10]=col1, [2,5,8,11]=col2
    acc0 = reduce_hi(fmaf(a0, wv4a.x, fmaf(a1, wv4a.w, fmaf(a2, wv4b.z, a3 * wv4c.y))));
    acc1 = reduce_hi(fmaf(a0, wv4a.y, fmaf(a1, wv4b.x, fmaf(a2, wv4b.w, a3 * wv4c.z))));
    acc2 = reduce_hi(fmaf(a0, wv4a.z, fmaf(a1, wv4b.y, fmaf(a2, wv4c.x, a3 * wv4c.w))));
  }

  // ---- epilogue: totals live in lanes 48-63; spread writes over 48-52
  if (lane >= 48 && lane < 51) {
    const int j = lane - 48;
    float acc = (j == 0) ? acc0 : ((j == 1) ? acc1 : acc2);
    acc += bpre;
    out[IMG_OFF + ray * 3 + j] = frcp(1.0f + __expf(-acc)) + (1.0f - wsum);
    out[FXYZ_OFF + ray * 3 + j] = (j == 0) ? fx_h : ((j == 1) ? fy_h : fz_h);
  }
  if (lane == 51) out[DEPTH_OFF + ray] = depth_h;
  if (lane == 52) { s_scal[wv][0] = prop_h; s_scal[wv][1] = dist_h; }
  __syncthreads();  // only cross-wave communication in the kernel
  if (threadIdx.x == 0) {
    float P = s_scal[0][0] + s_scal[1][0] + s_scal[2][0] + s_scal[3][0];
    float D = s_scal[0][1] + s_scal[1][1] + s_scal[2][1] + s_scal[3][1];
    if (use_atomic) {
      atomicAdd(out + PROP_OFF, P * (1.0f / ((float)NRAYS * 128.0f)));
      atomicAdd(out + DIST_OFF, D * (1.0f / (float)NRAYS));
    } else {
      ws_partials[blockIdx.x] = P;
      ws_partials[NBLK + blockIdx.x] = D;
    }
  }
}

__device__ __forceinline__ float wave_sum_shfl(float x) {
#pragma unroll
  for (int off = 1; off < 64; off <<= 1) x += __shfl_xor(x, off, 64);
  return x;
}

__global__ void __launch_bounds__(1024) reduce_partials(const float* __restrict__ ws,
                                                        float* __restrict__ out) {
  const float4* w4 = (const float4*)ws;
  float p = 0.0f, d = 0.0f;
  for (int i = threadIdx.x; i < NBLK / 4; i += 1024) {
    float4 a = w4[i];
    p += (a.x + a.y) + (a.z + a.w);
    float4 b = w4[NBLK / 4 + i];
    d += (b.x + b.y) + (b.z + b.w);
  }
  p = wave_sum_shfl(p);
  d = wave_sum_shfl(d);
  __shared__ float sp[16], sd[16];
  const int wv = threadIdx.x >> 6, lane = threadIdx.x & 63;
  if (lane == 0) { sp[wv] = p; sd[wv] = d; }
  __syncthreads();
  if (threadIdx.x == 0) {
    float P = 0.0f, D = 0.0f;
#pragma unroll
    for (int k = 0; k < 16; ++k) { P += sp[k]; D += sd[k]; }
    out[PROP_OFF] = P * (1.0f / ((float)NRAYS * 128.0f));
    out[DIST_OFF] = D * (1.0f / (float)NRAYS);
  }
}

extern "C" void kernel_launch(void* const* d_in, const int* in_sizes, int n_in,
                              void* d_out, int out_size, void* d_ws, size_t ws_size,
                              hipStream_t stream) {
  const float* rays_o = (const float*)d_in[0];
  const float* rays_d = (const float*)d_in[1];
  const float* aabb = (const float*)d_in[2];
  const float* sig_c = (const float*)d_in[3];
  const float* sig_f = (const float*)d_in[4];
  const float* colors = (const float*)d_in[5];
  const float* w_view = (const float*)d_in[6];
  const float* b_view = (const float*)d_in[7];
  float* out = (float*)d_out;
  float* wsf = (float*)d_ws;

  const bool use_ws = (ws_size >= (size_t)(2 * NBLK) * sizeof(float)) && (wsf != nullptr);
  if (!use_ws) {
    hipMemsetAsync(out + PROP_OFF, 0, 2 * sizeof(float), stream);
  }
  nerf_main<<<NBLK, 256, 0, stream>>>(rays_o, rays_d, aabb, sig_c, sig_f, colors,
                                      w_view, b_view, out, wsf, use_ws ? 0 : 1);
  if (use_ws) reduce_partials<<<1, 1024, 0, stream>>>(wsf, out);
}